// Round 4
// baseline (2601.292 us; speedup 1.0000x reference)
//
#include <hip/hip_runtime.h>
#include <hip/hip_bf16.h>

typedef __hip_bfloat16 bf16;

constexpr int B  = 64, T = 120, N = 24, M = 3, D = 32;
constexpr int NH = 2, FD = 16, FF = 64, L = 3;
constexpr float SCALE = 0.25f;   // 1/sqrt(FD)
constexpr int ST  = 33;          // padded LDS stride (spatial kernel)
constexpr int STQ = 33;          // Qs/O stride (temporal)
constexpr int STK = 36;          // Ks/Vs stride (temporal, 16B-aligned rows)
constexpr int SP  = 124;         // Sc bf16 row stride
constexpr int CH  = 30;          // temporal chunk rows (4 chunks x 30 = 120)

__device__ __forceinline__ float b2f(bf16 x) { return __bfloat162float(x); }

// ---------------------------------------------------------------------------
// Compose q/k/v chained linears in one launch: grid = 3*U blocks.
//   Wc[(fam*U+n)] = W1@W2, bc = b1@W2 + b2.
// ---------------------------------------------------------------------------
__global__ __launch_bounds__(256) void compose3_kernel(
    const float* __restrict__ W1q, const float* __restrict__ b1q,
    const float* __restrict__ W2q, const float* __restrict__ b2q,
    const float* __restrict__ W1k, const float* __restrict__ b1k,
    const float* __restrict__ W2k, const float* __restrict__ b2k,
    const float* __restrict__ W1v, const float* __restrict__ b1v,
    const float* __restrict__ W2v, const float* __restrict__ b2v,
    float* __restrict__ Wc, float* __restrict__ bc, int U) {
  int fam = blockIdx.x / U;
  int n   = blockIdx.x % U;
  const float* W1 = (fam == 0) ? W1q : (fam == 1) ? W1k : W1v;
  const float* b1 = (fam == 0) ? b1q : (fam == 1) ? b1k : b1v;
  const float* W2 = (fam == 0) ? W2q : (fam == 1) ? W2k : W2v;
  const float* b2 = (fam == 0) ? b2q : (fam == 1) ? b2k : b2v;
  const float* w1 = W1 + n * D * D;
  const float* w2 = W2 + n * D * D;
  float* wc = Wc + (size_t)(fam * U + n) * D * D;
  float* bcp = bc + (fam * U + n) * D;
  __shared__ float s1[D * D], s2[D * D];
  for (int i = threadIdx.x; i < D * D; i += 256) {
    s1[i] = w1[i];
    s2[i] = w2[i];
  }
  __syncthreads();
  for (int i = threadIdx.x; i < D * D; i += 256) {
    int d = i >> 5, f = i & 31;
    float acc = 0.f;
#pragma unroll
    for (int e = 0; e < D; ++e) acc += s1[d * D + e] * s2[e * D + f];
    wc[i] = acc;
  }
  if (threadIdx.x < D) {
    int f = threadIdx.x;
    float acc = b2[n * D + f];
#pragma unroll
    for (int e = 0; e < D; ++e) acc += b1[n * D + e] * s2[e * D + f];
    bcp[f] = acc;
  }
}

// ---------------------------------------------------------------------------
// E[b,t,n,d] = sum_m X[b,t,n*M+m]*E_W[n,m,d] + E_b[n,d] + pe[t,d]   (bf16 out)
// ---------------------------------------------------------------------------
__global__ __launch_bounds__(256) void embed_kernel(
    const float* __restrict__ X, const float* __restrict__ pe,
    const float* __restrict__ E_W, const float* __restrict__ E_b,
    bf16* __restrict__ E) {
  int idx = blockIdx.x * 256 + threadIdx.x;
  if (idx >= B * T * N * D) return;
  int d = idx & 31;
  int n = (idx >> 5) % N;
  int bt = idx / (D * N);
  int t = bt % T;
  const float* x = X + bt * (N * M) + n * M;
  float acc = E_b[n * D + d] + pe[t * D + d];
#pragma unroll
  for (int m = 0; m < M; ++m) acc += x[m] * E_W[(n * M + m) * D + d];
  E[idx] = __float2bfloat16(acc);
}

// ---------------------------------------------------------------------------
// Temporal attention v2, fused per (b, n).  Chunked two-pass softmax:
// 4 chunks of 30 query rows; scores computed fully parallel (4 lanes/row),
// stored bf16 in Sc; PV parallel over (row, f-quad).  LDS ~65 KB, 2 blk/CU.
// ---------------------------------------------------------------------------
__global__ __launch_bounds__(256) void temporal_kernel(
    const bf16* __restrict__ E, const float* __restrict__ WtC,
    const float* __restrict__ btC, const float* __restrict__ tm_Wo,
    const float* __restrict__ tm_bo, const float* __restrict__ ln_g,
    const float* __restrict__ ln_b, bf16* __restrict__ Tn) {
  int b = blockIdx.x / N;
  int n = blockIdx.x % N;
  __shared__ __align__(16) float Qs[T * STQ];   // Q, later O (per-chunk rows)
  __shared__ __align__(16) float Ks[T * STK];   // K, later pre-LN rows
  __shared__ __align__(16) float Vs[T * STK];
  __shared__ __align__(16) bf16  Sc[2 * 32 * SP];  // scores/P; Es staging (f32 view)
  __shared__ float Ls[64];
  int tid = threadIdx.x;
  int e = tid & 31;
  const bf16* Eg = E + ((size_t)b * T * N + n) * D;

  // --- stage Es (f32 view of Sc region, stride STQ) ---
  float* Ef = reinterpret_cast<float*>(Sc);
  for (int i = tid; i < T * D; i += 256) {
    int t = i >> 5, d = i & 31;
    Ef[t * STQ + d] = b2f(Eg[(size_t)t * N * D + d]);
  }
  __syncthreads();

  // --- QKV projections (weight columns in registers) ---
  {
    const float* wqg = WtC + (0 * N + n) * D * D;
    const float* wkg = WtC + (1 * N + n) * D * D;
    float wq[D], wk[D];
#pragma unroll
    for (int d = 0; d < D; ++d) { wq[d] = wqg[d * D + e]; wk[d] = wkg[d * D + e]; }
    float bqv = btC[(0 * N + n) * D + e];
    float bkv = btC[(1 * N + n) * D + e];
#pragma unroll
    for (int k = 0; k < T * D / 256; ++k) {
      int t = (tid + k * 256) >> 5;
      float aq = bqv, ak = bkv;
#pragma unroll
      for (int d = 0; d < D; ++d) {
        float x = Ef[t * STQ + d];
        aq += x * wq[d];
        ak += x * wk[d];
      }
      Qs[t * STQ + e] = aq;
      Ks[t * STK + e] = ak;
    }
  }
  {
    const float* wvg = WtC + (2 * N + n) * D * D;
    float wv[D];
#pragma unroll
    for (int d = 0; d < D; ++d) wv[d] = wvg[d * D + e];
    float bvv = btC[(2 * N + n) * D + e];
#pragma unroll
    for (int k = 0; k < T * D / 256; ++k) {
      int t = (tid + k * 256) >> 5;
      float av = bvv;
#pragma unroll
      for (int d = 0; d < D; ++d) av += Ef[t * STQ + d] * wv[d];
      Vs[t * STK + e] = av;
    }
  }
  __syncthreads();   // after this Sc region is free for scores

  // --- chunked attention ---
  int rs = tid >> 2;           // row slot 0..63 (active < 2*CH)
  int sl = tid & 3;            // key/f-quad slice
  int h  = (rs >= CH) ? 1 : 0;
  int r  = rs - h * CH;        // row within chunk
  int ho = h * FD;
  bool act = (rs < 2 * CH);

  for (int c = 0; c < 4; ++c) {
    int t0 = CH * c;
    int nk = t0 + CH;          // keys 0..nk-1
    int t  = t0 + r;
    bf16* srow = Sc + (h * CH + r) * SP;

    if (act) {
      // scores (this thread's key slice) + lane max
      float q[FD];
#pragma unroll
      for (int f = 0; f < FD; ++f) q[f] = Qs[t * STQ + ho + f];
      float m = -3e38f;
      for (int k = sl; k < nk; k += 4) {
        const float4* kr = (const float4*)&Ks[k * STK + ho];
        float4 k0 = kr[0], k1 = kr[1], k2 = kr[2], k3 = kr[3];
        float s = q[0]*k0.x + q[1]*k0.y + q[2]*k0.z + q[3]*k0.w
                + q[4]*k1.x + q[5]*k1.y + q[6]*k1.z + q[7]*k1.w
                + q[8]*k2.x + q[9]*k2.y + q[10]*k2.z + q[11]*k2.w
                + q[12]*k3.x + q[13]*k3.y + q[14]*k3.z + q[15]*k3.w;
        s = (k <= t) ? s * SCALE : -1e9f;
        srow[k] = __float2bfloat16(s);
        m = fmaxf(m, s);
      }
      // 4-lane max reduce
      m = fmaxf(m, __shfl_xor(m, 1, 64));
      m = fmaxf(m, __shfl_xor(m, 2, 64));
      // exp + sum (own slice, no barrier needed: self-written)
      float l = 0.f;
      for (int k = sl; k < nk; k += 4) {
        float p = __expf(b2f(srow[k]) - m);
        srow[k] = __float2bfloat16(p);
        l += p;
      }
      l += __shfl_xor(l, 1, 64);
      l += __shfl_xor(l, 2, 64);
      Ls[rs] = l;
    }
    __syncthreads();

    if (act) {
      // PV: this thread accumulates f-quad sl of row (h, r)
      float a0 = 0.f, a1 = 0.f, a2 = 0.f, a3 = 0.f;
      for (int k = 0; k < nk; ++k) {
        float p = b2f(srow[k]);
        const float4 v = *(const float4*)&Vs[k * STK + ho + sl * 4];
        a0 += p * v.x; a1 += p * v.y; a2 += p * v.z; a3 += p * v.w;
      }
      float rl = 1.f / Ls[rs];
      int o = t * STQ + ho + sl * 4;
      Qs[o + 0] = a0 * rl;
      Qs[o + 1] = a1 * rl;
      Qs[o + 2] = a2 * rl;
      Qs[o + 3] = a3 * rl;
    }
    __syncthreads();
  }

  // --- output projection + residual into Ks ---
  {
    const float* wog = tm_Wo + n * D * D;
    float wo[D];
#pragma unroll
    for (int d = 0; d < D; ++d) wo[d] = wog[d * D + e];
    float bov = tm_bo[n * D + e];
#pragma unroll
    for (int k = 0; k < T * D / 256; ++k) {
      int t = (tid + k * 256) >> 5;
      float a = bov;
#pragma unroll
      for (int d = 0; d < D; ++d) a += Qs[t * STQ + d] * wo[d];
      Ks[t * STK + e] = a + b2f(Eg[(size_t)t * N * D + e]);
    }
  }
  __syncthreads();

  // --- LayerNorm, one thread per row ---
  if (tid < T) {
    int t = tid;
    float mu = 0.f;
#pragma unroll
    for (int d = 0; d < D; ++d) mu += Ks[t * STK + d];
    mu *= (1.f / D);
    float var = 0.f;
#pragma unroll
    for (int d = 0; d < D; ++d) { float c = Ks[t * STK + d] - mu; var += c * c; }
    var *= (1.f / D);
    float r = rsqrtf(var + 1e-5f);
#pragma unroll
    for (int d = 0; d < D; ++d)
      Tn[((size_t)(b * T + t) * N + n) * D + d] =
          __float2bfloat16((Ks[t * STK + d] - mu) * r * ln_g[d] + ln_b[d]);
  }
}

// ---------------------------------------------------------------------------
// Spatial attention, fused per (b, t).  N=24 rows, 12.7 KB LDS.
// ---------------------------------------------------------------------------
__global__ __launch_bounds__(64) void spatial_kernel(
    const bf16* __restrict__ E, const float* __restrict__ WsC,
    const float* __restrict__ bsC, const float* __restrict__ sm_Wo,
    const float* __restrict__ sm_bo, const float* __restrict__ ln_g,
    const float* __restrict__ ln_b, bf16* __restrict__ Sn) {
  int b = blockIdx.x / T;
  int t = blockIdx.x % T;
  __shared__ float Es[N * ST], Ks[N * ST], Vs[N * ST], Os[N * ST];
  int tid = threadIdx.x;
  int e = tid & 31;

  for (int i = tid; i < N * D; i += 64) {
    int nn = i >> 5, d = i & 31;
    Es[nn * ST + d] = b2f(E[((size_t)(b * T + t) * N + nn) * D + d]);
  }
  __syncthreads();

  {
    const float* wqg = WsC + (0 * T + t) * D * D;
    const float* wkg = WsC + (1 * T + t) * D * D;
    float wq[D], wk[D];
#pragma unroll
    for (int d = 0; d < D; ++d) { wq[d] = wqg[d * D + e]; wk[d] = wkg[d * D + e]; }
    float bqv = bsC[(0 * T + t) * D + e];
    float bkv = bsC[(1 * T + t) * D + e];
#pragma unroll
    for (int k = 0; k < N * D / 64; ++k) {
      int nn = (tid + k * 64) >> 5;
      float aq = bqv, ak = bkv;
#pragma unroll
      for (int d = 0; d < D; ++d) {
        float x = Es[nn * ST + d];
        aq += x * wq[d];
        ak += x * wk[d];
      }
      Os[nn * ST + e] = aq;
      Ks[nn * ST + e] = ak;
    }
  }
  {
    const float* wvg = WsC + (2 * T + t) * D * D;
    float wv[D];
#pragma unroll
    for (int d = 0; d < D; ++d) wv[d] = wvg[d * D + e];
    float bvv = bsC[(2 * T + t) * D + e];
#pragma unroll
    for (int k = 0; k < N * D / 64; ++k) {
      int nn = (tid + k * 64) >> 5;
      float av = bvv;
#pragma unroll
      for (int d = 0; d < D; ++d) av += Es[nn * ST + d] * wv[d];
      Vs[nn * ST + e] = av;
    }
  }
  __syncthreads();

  if (tid < N * NH) {
    int nn = tid >> 1, h = tid & 1;
    int ho = h * FD;
    float q[FD];
#pragma unroll
    for (int f = 0; f < FD; ++f) q[f] = Os[nn * ST + ho + f];
    float sc[N];
    float m = -1e30f;
#pragma unroll
    for (int k = 0; k < N; ++k) {
      float s = 0.f;
#pragma unroll
      for (int f = 0; f < FD; ++f) s += q[f] * Ks[k * ST + ho + f];
      s *= SCALE;
      sc[k] = s;
      m = fmaxf(m, s);
    }
    float l = 0.f;
#pragma unroll
    for (int k = 0; k < N; ++k) { sc[k] = __expf(sc[k] - m); l += sc[k]; }
    float rl = 1.f / l;
#pragma unroll
    for (int f = 0; f < FD; ++f) {
      float a = 0.f;
#pragma unroll
      for (int k = 0; k < N; ++k) a += sc[k] * Vs[k * ST + ho + f];
      Os[nn * ST + ho + f] = a * rl;
    }
  }
  __syncthreads();

  {
    const float* wog = sm_Wo + t * D * D;
    float wo[D];
#pragma unroll
    for (int d = 0; d < D; ++d) wo[d] = wog[d * D + e];
    float bov = sm_bo[t * D + e];
#pragma unroll
    for (int k = 0; k < N * D / 64; ++k) {
      int nn = (tid + k * 64) >> 5;
      float a = bov;
#pragma unroll
      for (int d = 0; d < D; ++d) a += Os[nn * ST + d] * wo[d];
      Ks[nn * ST + e] = a + Es[nn * ST + e];
    }
  }
  __syncthreads();

  if (tid < N) {
    int nn = tid;
    float mu = 0.f;
#pragma unroll
    for (int d = 0; d < D; ++d) mu += Ks[nn * ST + d];
    mu *= (1.f / D);
    float var = 0.f;
#pragma unroll
    for (int d = 0; d < D; ++d) { float c = Ks[nn * ST + d] - mu; var += c * c; }
    var *= (1.f / D);
    float r = rsqrtf(var + 1e-5f);
#pragma unroll
    for (int d = 0; d < D; ++d)
      Sn[((size_t)(b * T + t) * N + nn) * D + d] =
          __float2bfloat16((Ks[nn * ST + d] - mu) * r * ln_g[d] + ln_b[d]);
  }
}

// ---------------------------------------------------------------------------
// ts = Tn + Sn; ff = relu(ts@W1+b1)@W2+b2; E = LN(ff + ts).  Row per thread.
// ---------------------------------------------------------------------------
__global__ __launch_bounds__(256) void ff_kernel(
    const bf16* __restrict__ Tn, const bf16* __restrict__ Sn,
    const float* __restrict__ W1, const float* __restrict__ b1,
    const float* __restrict__ W2, const float* __restrict__ b2,
    const float* __restrict__ ln_g, const float* __restrict__ ln_b,
    bf16* __restrict__ E) {
  __shared__ float w1[D * FF], w2[FF * D], bb1[FF], bb2[D], g[D], bbn[D];
  int tid = threadIdx.x;
  for (int i = tid; i < D * FF; i += 256) {
    w1[i] = W1[i];
    w2[i] = W2[i];
  }
  if (tid < FF) bb1[tid] = b1[tid];
  if (tid < D) {
    bb2[tid] = b2[tid];
    g[tid]   = ln_g[tid];
    bbn[tid] = ln_b[tid];
  }
  __syncthreads();
  int row = blockIdx.x * 256 + tid;
  if (row >= B * T * N) return;
  float ts[D];
#pragma unroll
  for (int d = 0; d < D; ++d)
    ts[d] = b2f(Tn[(size_t)row * D + d]) + b2f(Sn[(size_t)row * D + d]);
  float h[FF];
#pragma unroll
  for (int j = 0; j < FF; ++j) {
    float a = bb1[j];
#pragma unroll
    for (int d = 0; d < D; ++d) a += ts[d] * w1[d * FF + j];
    h[j] = fmaxf(a, 0.f);
  }
  float x[D];
  float mu = 0.f;
#pragma unroll
  for (int e = 0; e < D; ++e) {
    float a = bb2[e];
#pragma unroll
    for (int j = 0; j < FF; ++j) a += h[j] * w2[j * D + e];
    a += ts[e];
    x[e] = a;
    mu += a;
  }
  mu *= (1.f / D);
  float var = 0.f;
#pragma unroll
  for (int e = 0; e < D; ++e) { float c = x[e] - mu; var += c * c; }
  var *= (1.f / D);
  float r = rsqrtf(var + 1e-5f);
#pragma unroll
  for (int e = 0; e < D; ++e)
    E[(size_t)row * D + e] = __float2bfloat16((x[e] - mu) * r * g[e] + bbn[e]);
}

// ---------------------------------------------------------------------------
// out[b,t,n,m] = E[b,t,n,:]@op_W[n,:,m] + op_b[n,m] + X[b,t,n*M+m]  (f32 out)
// ---------------------------------------------------------------------------
__global__ __launch_bounds__(256) void out_kernel(
    const bf16* __restrict__ E, const float* __restrict__ op_W,
    const float* __restrict__ op_b, const float* __restrict__ X,
    float* __restrict__ out) {
  int idx = blockIdx.x * 256 + threadIdx.x;
  if (idx >= B * T * N * M) return;
  int m  = idx % M;
  int n  = (idx / M) % N;
  int bt = idx / (M * N);
  float acc = op_b[n * M + m];
  const bf16* e = E + ((size_t)bt * N + n) * D;
#pragma unroll
  for (int d = 0; d < D; ++d) acc += b2f(e[d]) * op_W[(n * D + d) * M + m];
  acc += X[idx];
  out[idx] = acc;
}

// ---------------------------------------------------------------------------
extern "C" void kernel_launch(void* const* d_in, const int* in_sizes, int n_in,
                              void* d_out, int out_size, void* d_ws, size_t ws_size,
                              hipStream_t stream) {
  const float* X     = (const float*)d_in[0];
  const float* pe    = (const float*)d_in[1];
  const float* E_W   = (const float*)d_in[2];
  const float* E_b   = (const float*)d_in[3];
  const float* tq_W  = (const float*)d_in[4];
  const float* tq_b  = (const float*)d_in[5];
  const float* tk_W  = (const float*)d_in[6];
  const float* tk_b  = (const float*)d_in[7];
  const float* tv_W  = (const float*)d_in[8];
  const float* tv_b  = (const float*)d_in[9];
  const float* tm_Wq = (const float*)d_in[10];
  const float* tm_bq = (const float*)d_in[11];
  const float* tm_Wk = (const float*)d_in[12];
  const float* tm_bk = (const float*)d_in[13];
  const float* tm_Wv = (const float*)d_in[14];
  const float* tm_bv = (const float*)d_in[15];
  const float* tm_Wo = (const float*)d_in[16];
  const float* tm_bo = (const float*)d_in[17];
  const float* sq_W  = (const float*)d_in[18];
  const float* sq_b  = (const float*)d_in[19];
  const float* sk_W  = (const float*)d_in[20];
  const float* sk_b  = (const float*)d_in[21];
  const float* sv_W  = (const float*)d_in[22];
  const float* sv_b  = (const float*)d_in[23];
  const float* sm_Wq = (const float*)d_in[24];
  const float* sm_bq = (const float*)d_in[25];
  const float* sm_Wk = (const float*)d_in[26];
  const float* sm_bk = (const float*)d_in[27];
  const float* sm_Wv = (const float*)d_in[28];
  const float* sm_bv = (const float*)d_in[29];
  const float* sm_Wo = (const float*)d_in[30];
  const float* sm_bo = (const float*)d_in[31];
  const float* ff1_W = (const float*)d_in[32];
  const float* ff1_b = (const float*)d_in[33];
  const float* ff2_W = (const float*)d_in[34];
  const float* ff2_b = (const float*)d_in[35];
  const float* ln_g  = (const float*)d_in[36];
  const float* ln_b  = (const float*)d_in[37];
  const float* op_W  = (const float*)d_in[38];
  const float* op_b  = (const float*)d_in[39];
  float* out = (float*)d_out;

  // workspace: f32 composed weights first, then bf16 activations (~37.2 MB)
  float* WtC = (float*)d_ws;                         // 3*N*D*D
  float* btC = WtC + 3 * N * D * D;                  // 3*N*D
  float* WsC = btC + 3 * N * D;                      // 3*T*D*D
  float* bsC = WsC + 3 * T * D * D;                  // 3*T*D
  size_t act = (size_t)B * T * N * D;
  bf16* Ebuf = (bf16*)(bsC + 3 * T * D);
  bf16* Tn   = Ebuf + act;
  bf16* Sn   = Tn + act;

  compose3_kernel<<<3 * N, 256, 0, stream>>>(
      tq_W, tq_b, tm_Wq, tm_bq, tk_W, tk_b, tm_Wk, tm_bk,
      tv_W, tv_b, tm_Wv, tm_bv, WtC, btC, N);
  compose3_kernel<<<3 * T, 256, 0, stream>>>(
      sq_W, sq_b, sm_Wq, sm_bq, sk_W, sk_b, sm_Wk, sm_bk,
      sv_W, sv_b, sm_Wv, sm_bv, WsC, bsC, T);

  embed_kernel<<<(B * T * N * D) / 256, 256, 0, stream>>>(X, pe, E_W, E_b, Ebuf);

  for (int l = 0; l < L; ++l) {
    temporal_kernel<<<B * N, 256, 0, stream>>>(Ebuf, WtC, btC, tm_Wo, tm_bo, ln_g, ln_b, Tn);
    spatial_kernel<<<B * T, 64, 0, stream>>>(Ebuf, WsC, bsC, sm_Wo, sm_bo, ln_g, ln_b, Sn);
    ff_kernel<<<(B * T * N) / 256, 256, 0, stream>>>(Tn, Sn, ff1_W, ff1_b, ff2_W, ff2_b, ln_g, ln_b, Ebuf);
  }

  out_kernel<<<(B * T * N * M) / 256, 256, 0, stream>>>(Ebuf, op_W, op_b, X, out);
}

// Round 5
// 2578.718 us; speedup vs baseline: 1.0088x; 1.0088x over previous
//
#include <hip/hip_runtime.h>
#include <hip/hip_bf16.h>

typedef __hip_bfloat16 bf16;

constexpr int B  = 64, T = 120, N = 24, M = 3, D = 32;
constexpr int NH = 2, FD = 16, FF = 64, L = 3;
constexpr float SCALE = 0.25f;   // 1/sqrt(FD)
constexpr int ST  = 33;          // padded LDS stride (spatial kernel)
constexpr int STQ = 33;          // Qs/O stride (temporal)
constexpr int STK = 36;          // Ks/Vs stride (temporal, 16B-aligned rows)
constexpr int SP  = 124;         // Sc bf16 row stride
constexpr int CH  = 30;          // temporal chunk rows (4 chunks x 30 = 120)

__device__ __forceinline__ float b2f(bf16 x) { return __bfloat162float(x); }

// ---------------------------------------------------------------------------
// Compose q/k/v chained linears in one launch: grid = 3*U blocks.
//   Wc[(fam*U+n)] = W1@W2, bc = b1@W2 + b2.
// ---------------------------------------------------------------------------
__global__ __launch_bounds__(256) void compose3_kernel(
    const float* __restrict__ W1q, const float* __restrict__ b1q,
    const float* __restrict__ W2q, const float* __restrict__ b2q,
    const float* __restrict__ W1k, const float* __restrict__ b1k,
    const float* __restrict__ W2k, const float* __restrict__ b2k,
    const float* __restrict__ W1v, const float* __restrict__ b1v,
    const float* __restrict__ W2v, const float* __restrict__ b2v,
    float* __restrict__ Wc, float* __restrict__ bc, int U) {
  int fam = blockIdx.x / U;
  int n   = blockIdx.x % U;
  const float* W1 = (fam == 0) ? W1q : (fam == 1) ? W1k : W1v;
  const float* b1 = (fam == 0) ? b1q : (fam == 1) ? b1k : b1v;
  const float* W2 = (fam == 0) ? W2q : (fam == 1) ? W2k : W2v;
  const float* b2 = (fam == 0) ? b2q : (fam == 1) ? b2k : b2v;
  const float* w1 = W1 + n * D * D;
  const float* w2 = W2 + n * D * D;
  float* wc = Wc + (size_t)(fam * U + n) * D * D;
  float* bcp = bc + (fam * U + n) * D;
  __shared__ float s1[D * D], s2[D * D];
  for (int i = threadIdx.x; i < D * D; i += 256) {
    s1[i] = w1[i];
    s2[i] = w2[i];
  }
  __syncthreads();
  for (int i = threadIdx.x; i < D * D; i += 256) {
    int d = i >> 5, f = i & 31;
    float acc = 0.f;
#pragma unroll
    for (int e = 0; e < D; ++e) acc += s1[d * D + e] * s2[e * D + f];
    wc[i] = acc;
  }
  if (threadIdx.x < D) {
    int f = threadIdx.x;
    float acc = b2[n * D + f];
#pragma unroll
    for (int e = 0; e < D; ++e) acc += b1[n * D + e] * s2[e * D + f];
    bcp[f] = acc;
  }
}

// ---------------------------------------------------------------------------
// E[b,t,n,d] = sum_m X[b,t,n*M+m]*E_W[n,m,d] + E_b[n,d] + pe[t,d]   (bf16 out)
// ---------------------------------------------------------------------------
__global__ __launch_bounds__(256) void embed_kernel(
    const float* __restrict__ X, const float* __restrict__ pe,
    const float* __restrict__ E_W, const float* __restrict__ E_b,
    bf16* __restrict__ E) {
  int idx = blockIdx.x * 256 + threadIdx.x;
  if (idx >= B * T * N * D) return;
  int d = idx & 31;
  int n = (idx >> 5) % N;
  int bt = idx / (D * N);
  int t = bt % T;
  const float* x = X + bt * (N * M) + n * M;
  float acc = E_b[n * D + d] + pe[t * D + d];
#pragma unroll
  for (int m = 0; m < M; ++m) acc += x[m] * E_W[(n * M + m) * D + d];
  E[idx] = __float2bfloat16(acc);
}

// ---------------------------------------------------------------------------
// Temporal attention v2.1, fused per (b, n).  Chunked two-pass softmax.
// KEY: chunk loop is "#pragma unroll 1" — in v2 it unrolled, made nk
// compile-time, fully unrolled the k-loops, blew past the VGPR file and
// spilled ~600 KB/block to scratch (926 MB HBM traffic, 2.5x slowdown).
// ---------------------------------------------------------------------------
__global__ __launch_bounds__(256) void temporal_kernel(
    const bf16* __restrict__ E, const float* __restrict__ WtC,
    const float* __restrict__ btC, const float* __restrict__ tm_Wo,
    const float* __restrict__ tm_bo, const float* __restrict__ ln_g,
    const float* __restrict__ ln_b, bf16* __restrict__ Tn) {
  int b = blockIdx.x / N;
  int n = blockIdx.x % N;
  __shared__ __align__(16) float Qs[T * STQ];   // Q, later O
  __shared__ __align__(16) float Ks[T * STK];   // K, later pre-LN rows
  __shared__ __align__(16) float Vs[T * STK];
  __shared__ __align__(16) bf16  Sc[2 * 32 * SP];  // scores/P; Es staging (f32 view)
  __shared__ float Ls[64];
  int tid = threadIdx.x;
  int e = tid & 31;
  const bf16* Eg = E + ((size_t)b * T * N + n) * D;

  // --- stage Es (f32 view of Sc region, stride STQ) ---
  float* Ef = reinterpret_cast<float*>(Sc);
  for (int i = tid; i < T * D; i += 256) {
    int t = i >> 5, d = i & 31;
    Ef[t * STQ + d] = b2f(Eg[(size_t)t * N * D + d]);
  }
  __syncthreads();

  // --- QKV projections (weight columns in registers) ---
  {
    const float* wqg = WtC + (0 * N + n) * D * D;
    const float* wkg = WtC + (1 * N + n) * D * D;
    float wq[D], wk[D];
#pragma unroll
    for (int d = 0; d < D; ++d) { wq[d] = wqg[d * D + e]; wk[d] = wkg[d * D + e]; }
    float bqv = btC[(0 * N + n) * D + e];
    float bkv = btC[(1 * N + n) * D + e];
#pragma unroll
    for (int k = 0; k < T * D / 256; ++k) {
      int t = (tid + k * 256) >> 5;
      float aq = bqv, ak = bkv;
#pragma unroll
      for (int d = 0; d < D; ++d) {
        float x = Ef[t * STQ + d];
        aq += x * wq[d];
        ak += x * wk[d];
      }
      Qs[t * STQ + e] = aq;
      Ks[t * STK + e] = ak;
    }
  }
  {
    const float* wvg = WtC + (2 * N + n) * D * D;
    float wv[D];
#pragma unroll
    for (int d = 0; d < D; ++d) wv[d] = wvg[d * D + e];
    float bvv = btC[(2 * N + n) * D + e];
#pragma unroll
    for (int k = 0; k < T * D / 256; ++k) {
      int t = (tid + k * 256) >> 5;
      float av = bvv;
#pragma unroll
      for (int d = 0; d < D; ++d) av += Ef[t * STQ + d] * wv[d];
      Vs[t * STK + e] = av;
    }
  }
  __syncthreads();   // after this Sc region is free for scores

  // --- chunked attention ---
  int rs = tid >> 2;           // row slot 0..63 (active < 2*CH)
  int sl = tid & 3;            // key/f-quad slice
  int h  = (rs >= CH) ? 1 : 0;
  int r  = rs - h * CH;        // row within chunk
  int ho = h * FD;
  bool act = (rs < 2 * CH);

#pragma unroll 1               // DO NOT unroll: keeps nk runtime, stops the
  for (int c = 0; c < 4; ++c) {  // k-loop full-unroll -> VGPR spill cascade
    int t0 = CH * c;
    int nk = t0 + CH;          // keys 0..nk-1
    int t  = t0 + r;
    bf16* srow = Sc + (h * CH + r) * SP;

    if (act) {
      // scores (this thread's key slice) + lane max
      float q[FD];
#pragma unroll
      for (int f = 0; f < FD; ++f) q[f] = Qs[t * STQ + ho + f];
      float m = -3e38f;
#pragma unroll 2
      for (int k = sl; k < nk; k += 4) {
        const float4* kr = (const float4*)&Ks[k * STK + ho];
        float4 k0 = kr[0], k1 = kr[1], k2 = kr[2], k3 = kr[3];
        float s = q[0]*k0.x + q[1]*k0.y + q[2]*k0.z + q[3]*k0.w
                + q[4]*k1.x + q[5]*k1.y + q[6]*k1.z + q[7]*k1.w
                + q[8]*k2.x + q[9]*k2.y + q[10]*k2.z + q[11]*k2.w
                + q[12]*k3.x + q[13]*k3.y + q[14]*k3.z + q[15]*k3.w;
        s = (k <= t) ? s * SCALE : -1e9f;
        srow[k] = __float2bfloat16(s);
        m = fmaxf(m, s);
      }
      // 4-lane max reduce
      m = fmaxf(m, __shfl_xor(m, 1, 64));
      m = fmaxf(m, __shfl_xor(m, 2, 64));
      // exp + sum (own slice, no barrier needed: self-written)
      float l = 0.f;
#pragma unroll 2
      for (int k = sl; k < nk; k += 4) {
        float p = __expf(b2f(srow[k]) - m);
        srow[k] = __float2bfloat16(p);
        l += p;
      }
      l += __shfl_xor(l, 1, 64);
      l += __shfl_xor(l, 2, 64);
      Ls[rs] = l;
    }
    __syncthreads();

    if (act) {
      // PV: this thread accumulates f-quad sl of row (h, r)
      float a0 = 0.f, a1 = 0.f, a2 = 0.f, a3 = 0.f;
#pragma unroll 4
      for (int k = 0; k < nk; ++k) {
        float p = b2f(srow[k]);
        const float4 v = *(const float4*)&Vs[k * STK + ho + sl * 4];
        a0 += p * v.x; a1 += p * v.y; a2 += p * v.z; a3 += p * v.w;
      }
      float rl = 1.f / Ls[rs];
      int o = t * STQ + ho + sl * 4;
      Qs[o + 0] = a0 * rl;
      Qs[o + 1] = a1 * rl;
      Qs[o + 2] = a2 * rl;
      Qs[o + 3] = a3 * rl;
    }
    __syncthreads();
  }

  // --- output projection + residual into Ks ---
  {
    const float* wog = tm_Wo + n * D * D;
    float wo[D];
#pragma unroll
    for (int d = 0; d < D; ++d) wo[d] = wog[d * D + e];
    float bov = tm_bo[n * D + e];
#pragma unroll
    for (int k = 0; k < T * D / 256; ++k) {
      int t = (tid + k * 256) >> 5;
      float a = bov;
#pragma unroll
      for (int d = 0; d < D; ++d) a += Qs[t * STQ + d] * wo[d];
      Ks[t * STK + e] = a + b2f(Eg[(size_t)t * N * D + e]);
    }
  }
  __syncthreads();

  // --- LayerNorm, one thread per row ---
  if (tid < T) {
    int t = tid;
    float mu = 0.f;
#pragma unroll
    for (int d = 0; d < D; ++d) mu += Ks[t * STK + d];
    mu *= (1.f / D);
    float var = 0.f;
#pragma unroll
    for (int d = 0; d < D; ++d) { float c = Ks[t * STK + d] - mu; var += c * c; }
    var *= (1.f / D);
    float r = rsqrtf(var + 1e-5f);
#pragma unroll
    for (int d = 0; d < D; ++d)
      Tn[((size_t)(b * T + t) * N + n) * D + d] =
          __float2bfloat16((Ks[t * STK + d] - mu) * r * ln_g[d] + ln_b[d]);
  }
}

// ---------------------------------------------------------------------------
// Spatial attention, fused per (b, t).  N=24 rows, 12.7 KB LDS.
// ---------------------------------------------------------------------------
__global__ __launch_bounds__(64) void spatial_kernel(
    const bf16* __restrict__ E, const float* __restrict__ WsC,
    const float* __restrict__ bsC, const float* __restrict__ sm_Wo,
    const float* __restrict__ sm_bo, const float* __restrict__ ln_g,
    const float* __restrict__ ln_b, bf16* __restrict__ Sn) {
  int b = blockIdx.x / T;
  int t = blockIdx.x % T;
  __shared__ float Es[N * ST], Ks[N * ST], Vs[N * ST], Os[N * ST];
  int tid = threadIdx.x;
  int e = tid & 31;

  for (int i = tid; i < N * D; i += 64) {
    int nn = i >> 5, d = i & 31;
    Es[nn * ST + d] = b2f(E[((size_t)(b * T + t) * N + nn) * D + d]);
  }
  __syncthreads();

  {
    const float* wqg = WsC + (0 * T + t) * D * D;
    const float* wkg = WsC + (1 * T + t) * D * D;
    float wq[D], wk[D];
#pragma unroll
    for (int d = 0; d < D; ++d) { wq[d] = wqg[d * D + e]; wk[d] = wkg[d * D + e]; }
    float bqv = bsC[(0 * T + t) * D + e];
    float bkv = bsC[(1 * T + t) * D + e];
#pragma unroll
    for (int k = 0; k < N * D / 64; ++k) {
      int nn = (tid + k * 64) >> 5;
      float aq = bqv, ak = bkv;
#pragma unroll
      for (int d = 0; d < D; ++d) {
        float x = Es[nn * ST + d];
        aq += x * wq[d];
        ak += x * wk[d];
      }
      Os[nn * ST + e] = aq;
      Ks[nn * ST + e] = ak;
    }
  }
  {
    const float* wvg = WsC + (2 * T + t) * D * D;
    float wv[D];
#pragma unroll
    for (int d = 0; d < D; ++d) wv[d] = wvg[d * D + e];
    float bvv = bsC[(2 * T + t) * D + e];
#pragma unroll
    for (int k = 0; k < N * D / 64; ++k) {
      int nn = (tid + k * 64) >> 5;
      float av = bvv;
#pragma unroll
      for (int d = 0; d < D; ++d) av += Es[nn * ST + d] * wv[d];
      Vs[nn * ST + e] = av;
    }
  }
  __syncthreads();

  if (tid < N * NH) {
    int nn = tid >> 1, h = tid & 1;
    int ho = h * FD;
    float q[FD];
#pragma unroll
    for (int f = 0; f < FD; ++f) q[f] = Os[nn * ST + ho + f];
    float sc[N];
    float m = -1e30f;
#pragma unroll
    for (int k = 0; k < N; ++k) {
      float s = 0.f;
#pragma unroll
      for (int f = 0; f < FD; ++f) s += q[f] * Ks[k * ST + ho + f];
      s *= SCALE;
      sc[k] = s;
      m = fmaxf(m, s);
    }
    float l = 0.f;
#pragma unroll
    for (int k = 0; k < N; ++k) { sc[k] = __expf(sc[k] - m); l += sc[k]; }
    float rl = 1.f / l;
#pragma unroll
    for (int f = 0; f < FD; ++f) {
      float a = 0.f;
#pragma unroll
      for (int k = 0; k < N; ++k) a += sc[k] * Vs[k * ST + ho + f];
      Os[nn * ST + ho + f] = a * rl;
    }
  }
  __syncthreads();

  {
    const float* wog = sm_Wo + t * D * D;
    float wo[D];
#pragma unroll
    for (int d = 0; d < D; ++d) wo[d] = wog[d * D + e];
    float bov = sm_bo[t * D + e];
#pragma unroll
    for (int k = 0; k < N * D / 64; ++k) {
      int nn = (tid + k * 64) >> 5;
      float a = bov;
#pragma unroll
      for (int d = 0; d < D; ++d) a += Os[nn * ST + d] * wo[d];
      Ks[nn * ST + e] = a + Es[nn * ST + e];
    }
  }
  __syncthreads();

  if (tid < N) {
    int nn = tid;
    float mu = 0.f;
#pragma unroll
    for (int d = 0; d < D; ++d) mu += Ks[nn * ST + d];
    mu *= (1.f / D);
    float var = 0.f;
#pragma unroll
    for (int d = 0; d < D; ++d) { float c = Ks[nn * ST + d] - mu; var += c * c; }
    var *= (1.f / D);
    float r = rsqrtf(var + 1e-5f);
#pragma unroll
    for (int d = 0; d < D; ++d)
      Sn[((size_t)(b * T + t) * N + nn) * D + d] =
          __float2bfloat16((Ks[nn * ST + d] - mu) * r * ln_g[d] + ln_b[d]);
  }
}

// ---------------------------------------------------------------------------
// ts = Tn + Sn; ff = relu(ts@W1+b1)@W2+b2; E = LN(ff + ts).  Row per thread.
// ---------------------------------------------------------------------------
__global__ __launch_bounds__(256) void ff_kernel(
    const bf16* __restrict__ Tn, const bf16* __restrict__ Sn,
    const float* __restrict__ W1, const float* __restrict__ b1,
    const float* __restrict__ W2, const float* __restrict__ b2,
    const float* __restrict__ ln_g, const float* __restrict__ ln_b,
    bf16* __restrict__ E) {
  __shared__ float w1[D * FF], w2[FF * D], bb1[FF], bb2[D], g[D], bbn[D];
  int tid = threadIdx.x;
  for (int i = tid; i < D * FF; i += 256) {
    w1[i] = W1[i];
    w2[i] = W2[i];
  }
  if (tid < FF) bb1[tid] = b1[tid];
  if (tid < D) {
    bb2[tid] = b2[tid];
    g[tid]   = ln_g[tid];
    bbn[tid] = ln_b[tid];
  }
  __syncthreads();
  int row = blockIdx.x * 256 + tid;
  if (row >= B * T * N) return;
  float ts[D];
#pragma unroll
  for (int d = 0; d < D; ++d)
    ts[d] = b2f(Tn[(size_t)row * D + d]) + b2f(Sn[(size_t)row * D + d]);
  float h[FF];
#pragma unroll
  for (int j = 0; j < FF; ++j) {
    float a = bb1[j];
#pragma unroll
    for (int d = 0; d < D; ++d) a += ts[d] * w1[d * FF + j];
    h[j] = fmaxf(a, 0.f);
  }
  float x[D];
  float mu = 0.f;
#pragma unroll
  for (int e = 0; e < D; ++e) {
    float a = bb2[e];
#pragma unroll
    for (int j = 0; j < FF; ++j) a += h[j] * w2[j * D + e];
    a += ts[e];
    x[e] = a;
    mu += a;
  }
  mu *= (1.f / D);
  float var = 0.f;
#pragma unroll
  for (int e = 0; e < D; ++e) { float c = x[e] - mu; var += c * c; }
  var *= (1.f / D);
  float r = rsqrtf(var + 1e-5f);
#pragma unroll
  for (int e = 0; e < D; ++e)
    E[(size_t)row * D + e] = __float2bfloat16((x[e] - mu) * r * g[e] + bbn[e]);
}

// ---------------------------------------------------------------------------
// out[b,t,n,m] = E[b,t,n,:]@op_W[n,:,m] + op_b[n,m] + X[b,t,n*M+m]  (f32 out)
// ---------------------------------------------------------------------------
__global__ __launch_bounds__(256) void out_kernel(
    const bf16* __restrict__ E, const float* __restrict__ op_W,
    const float* __restrict__ op_b, const float* __restrict__ X,
    float* __restrict__ out) {
  int idx = blockIdx.x * 256 + threadIdx.x;
  if (idx >= B * T * N * M) return;
  int m  = idx % M;
  int n  = (idx / M) % N;
  int bt = idx / (M * N);
  float acc = op_b[n * M + m];
  const bf16* e = E + ((size_t)bt * N + n) * D;
#pragma unroll
  for (int d = 0; d < D; ++d) acc += b2f(e[d]) * op_W[(n * D + d) * M + m];
  acc += X[idx];
  out[idx] = acc;
}

// ---------------------------------------------------------------------------
extern "C" void kernel_launch(void* const* d_in, const int* in_sizes, int n_in,
                              void* d_out, int out_size, void* d_ws, size_t ws_size,
                              hipStream_t stream) {
  const float* X     = (const float*)d_in[0];
  const float* pe    = (const float*)d_in[1];
  const float* E_W   = (const float*)d_in[2];
  const float* E_b   = (const float*)d_in[3];
  const float* tq_W  = (const float*)d_in[4];
  const float* tq_b  = (const float*)d_in[5];
  const float* tk_W  = (const float*)d_in[6];
  const float* tk_b  = (const float*)d_in[7];
  const float* tv_W  = (const float*)d_in[8];
  const float* tv_b  = (const float*)d_in[9];
  const float* tm_Wq = (const float*)d_in[10];
  const float* tm_bq = (const float*)d_in[11];
  const float* tm_Wk = (const float*)d_in[12];
  const float* tm_bk = (const float*)d_in[13];
  const float* tm_Wv = (const float*)d_in[14];
  const float* tm_bv = (const float*)d_in[15];
  const float* tm_Wo = (const float*)d_in[16];
  const float* tm_bo = (const float*)d_in[17];
  const float* sq_W  = (const float*)d_in[18];
  const float* sq_b  = (const float*)d_in[19];
  const float* sk_W  = (const float*)d_in[20];
  const float* sk_b  = (const float*)d_in[21];
  const float* sv_W  = (const float*)d_in[22];
  const float* sv_b  = (const float*)d_in[23];
  const float* sm_Wq = (const float*)d_in[24];
  const float* sm_bq = (const float*)d_in[25];
  const float* sm_Wk = (const float*)d_in[26];
  const float* sm_bk = (const float*)d_in[27];
  const float* sm_Wv = (const float*)d_in[28];
  const float* sm_bv = (const float*)d_in[29];
  const float* sm_Wo = (const float*)d_in[30];
  const float* sm_bo = (const float*)d_in[31];
  const float* ff1_W = (const float*)d_in[32];
  const float* ff1_b = (const float*)d_in[33];
  const float* ff2_W = (const float*)d_in[34];
  const float* ff2_b = (const float*)d_in[35];
  const float* ln_g  = (const float*)d_in[36];
  const float* ln_b  = (const float*)d_in[37];
  const float* op_W  = (const float*)d_in[38];
  const float* op_b  = (const float*)d_in[39];
  float* out = (float*)d_out;

  // workspace: f32 composed weights first, then bf16 activations (~37.2 MB)
  float* WtC = (float*)d_ws;                         // 3*N*D*D
  float* btC = WtC + 3 * N * D * D;                  // 3*N*D
  float* WsC = btC + 3 * N * D;                      // 3*T*D*D
  float* bsC = WsC + 3 * T * D * D;                  // 3*T*D
  size_t act = (size_t)B * T * N * D;
  bf16* Ebuf = (bf16*)(bsC + 3 * T * D);
  bf16* Tn   = Ebuf + act;
  bf16* Sn   = Tn + act;

  compose3_kernel<<<3 * N, 256, 0, stream>>>(
      tq_W, tq_b, tm_Wq, tm_bq, tk_W, tk_b, tm_Wk, tm_bk,
      tv_W, tv_b, tm_Wv, tm_bv, WtC, btC, N);
  compose3_kernel<<<3 * T, 256, 0, stream>>>(
      sq_W, sq_b, sm_Wq, sm_bq, sk_W, sk_b, sm_Wk, sm_bk,
      sv_W, sv_b, sm_Wv, sm_bv, WsC, bsC, T);

  embed_kernel<<<(B * T * N * D) / 256, 256, 0, stream>>>(X, pe, E_W, E_b, Ebuf);

  for (int l = 0; l < L; ++l) {
    temporal_kernel<<<B * N, 256, 0, stream>>>(Ebuf, WtC, btC, tm_Wo, tm_bo, ln_g, ln_b, Tn);
    spatial_kernel<<<B * T, 64, 0, stream>>>(Ebuf, WsC, bsC, sm_Wo, sm_bo, ln_g, ln_b, Sn);
    ff_kernel<<<(B * T * N) / 256, 256, 0, stream>>>(Tn, Sn, ff1_W, ff1_b, ff2_W, ff2_b, ln_g, ln_b, Ebuf);
  }

  out_kernel<<<(B * T * N * M) / 256, 256, 0, stream>>>(Ebuf, op_W, op_b, X, out);
}

// Round 6
// 1390.672 us; speedup vs baseline: 1.8705x; 1.8543x over previous
//
#include <hip/hip_runtime.h>
#include <hip/hip_bf16.h>

typedef __hip_bfloat16 bf16;

constexpr int B  = 64, T = 120, N = 24, M = 3, D = 32;
constexpr int NH = 2, FD = 16, FF = 64, L = 3;
constexpr float SCALE = 0.25f;   // 1/sqrt(FD)
constexpr int ST  = 33;          // padded LDS stride (spatial kernel, f32)
constexpr int STE = 34;          // Es/Os bf16 row stride (68 B)
constexpr int STK = 36;          // Ks/Vs f32 row stride (144 B, 16B-aligned)

__device__ __forceinline__ float b2f(bf16 x) { return __bfloat162float(x); }

// ---------------------------------------------------------------------------
// Compose q/k/v chained linears in one launch: grid = 3*U blocks.
//   Wc[(fam*U+n)] = W1@W2, bc = b1@W2 + b2.
// ---------------------------------------------------------------------------
__global__ __launch_bounds__(256) void compose3_kernel(
    const float* __restrict__ W1q, const float* __restrict__ b1q,
    const float* __restrict__ W2q, const float* __restrict__ b2q,
    const float* __restrict__ W1k, const float* __restrict__ b1k,
    const float* __restrict__ W2k, const float* __restrict__ b2k,
    const float* __restrict__ W1v, const float* __restrict__ b1v,
    const float* __restrict__ W2v, const float* __restrict__ b2v,
    float* __restrict__ Wc, float* __restrict__ bc, int U) {
  int fam = blockIdx.x / U;
  int n   = blockIdx.x % U;
  const float* W1 = (fam == 0) ? W1q : (fam == 1) ? W1k : W1v;
  const float* b1 = (fam == 0) ? b1q : (fam == 1) ? b1k : b1v;
  const float* W2 = (fam == 0) ? W2q : (fam == 1) ? W2k : W2v;
  const float* b2 = (fam == 0) ? b2q : (fam == 1) ? b2k : b2v;
  const float* w1 = W1 + n * D * D;
  const float* w2 = W2 + n * D * D;
  float* wc = Wc + (size_t)(fam * U + n) * D * D;
  float* bcp = bc + (fam * U + n) * D;
  __shared__ float s1[D * D], s2[D * D];
  for (int i = threadIdx.x; i < D * D; i += 256) {
    s1[i] = w1[i];
    s2[i] = w2[i];
  }
  __syncthreads();
  for (int i = threadIdx.x; i < D * D; i += 256) {
    int d = i >> 5, f = i & 31;
    float acc = 0.f;
#pragma unroll
    for (int e = 0; e < D; ++e) acc += s1[d * D + e] * s2[e * D + f];
    wc[i] = acc;
  }
  if (threadIdx.x < D) {
    int f = threadIdx.x;
    float acc = b2[n * D + f];
#pragma unroll
    for (int e = 0; e < D; ++e) acc += b1[n * D + e] * s2[e * D + f];
    bcp[f] = acc;
  }
}

// ---------------------------------------------------------------------------
// E[b,t,n,d] = sum_m X[b,t,n*M+m]*E_W[n,m,d] + E_b[n,d] + pe[t,d]   (bf16 out)
// ---------------------------------------------------------------------------
__global__ __launch_bounds__(256) void embed_kernel(
    const float* __restrict__ X, const float* __restrict__ pe,
    const float* __restrict__ E_W, const float* __restrict__ E_b,
    bf16* __restrict__ E) {
  int idx = blockIdx.x * 256 + threadIdx.x;
  if (idx >= B * T * N * D) return;
  int d = idx & 31;
  int n = (idx >> 5) % N;
  int bt = idx / (D * N);
  int t = bt % T;
  const float* x = X + bt * (N * M) + n * M;
  float acc = E_b[n * D + d] + pe[t * D + d];
#pragma unroll
  for (int m = 0; m < M; ++m) acc += x[m] * E_W[(n * M + m) * D + d];
  E[idx] = __float2bfloat16(acc);
}

// ---------------------------------------------------------------------------
// Temporal attention v3, fused per (b, n).  Round-3 skeleton (144 VGPR proven)
// + balanced 2-way-split softmax: thread = (t<60, h, key-parity) handles rows
// t AND 119-t -> every thread ~60 serial keys (was 1..120, imbalanced), merge
// via __shfl_xor(1).  Es/Os stored bf16: LDS 49.7 KB -> 3 blocks/CU.
// ---------------------------------------------------------------------------
__global__ __launch_bounds__(256) void temporal_kernel(
    const bf16* __restrict__ E, const float* __restrict__ WtC,
    const float* __restrict__ btC, const float* __restrict__ tm_Wo,
    const float* __restrict__ tm_bo, const float* __restrict__ ln_g,
    const float* __restrict__ ln_b, bf16* __restrict__ Tn) {
  int b = blockIdx.x / N;
  int n = blockIdx.x % N;
  __shared__ __align__(16) bf16  Es[T * STE];   // staged E (bf16)
  __shared__ __align__(16) bf16  Os[T * STE];   // Q, then O (bf16)
  __shared__ __align__(16) float Ks[T * STK];   // K, later pre-LN rows
  __shared__ __align__(16) float Vs[T * STK];
  int tid = threadIdx.x;
  int e = tid & 31;
  const bf16* Eg = E + ((size_t)b * T * N + n) * D;

  // --- stage Es (raw bf16 copy) ---
  for (int i = tid; i < T * D; i += 256) {
    int t = i >> 5, d = i & 31;
    Es[t * STE + d] = Eg[(size_t)t * N * D + d];
  }
  __syncthreads();

  // --- Q (into Os) and K projections (weight columns in registers) ---
  {
    const float* wqg = WtC + (0 * N + n) * D * D;
    const float* wkg = WtC + (1 * N + n) * D * D;
    float wq[D], wk[D];
#pragma unroll
    for (int d = 0; d < D; ++d) { wq[d] = wqg[d * D + e]; wk[d] = wkg[d * D + e]; }
    float bqv = btC[(0 * N + n) * D + e];
    float bkv = btC[(1 * N + n) * D + e];
#pragma unroll
    for (int k = 0; k < T * D / 256; ++k) {
      int t = (tid + k * 256) >> 5;
      float aq = bqv, ak = bkv;
#pragma unroll
      for (int d = 0; d < D; ++d) {
        float x = b2f(Es[t * STE + d]);
        aq += x * wq[d];
        ak += x * wk[d];
      }
      Os[t * STE + e] = __float2bfloat16(aq);
      Ks[t * STK + e] = ak;
    }
  }
  // --- V projection ---
  {
    const float* wvg = WtC + (2 * N + n) * D * D;
    float wv[D];
#pragma unroll
    for (int d = 0; d < D; ++d) wv[d] = wvg[d * D + e];
    float bvv = btC[(2 * N + n) * D + e];
#pragma unroll
    for (int k = 0; k < T * D / 256; ++k) {
      int t = (tid + k * 256) >> 5;
      float av = bvv;
#pragma unroll
      for (int d = 0; d < D; ++d) av += b2f(Es[t * STE + d]) * wv[d];
      Vs[t * STK + e] = av;
    }
  }
  __syncthreads();

  // --- balanced split online softmax ---
  // tid = tq*4 + h*2 + par, tq in [0,60): rows tq and 119-tq, keys k==par (mod 2)
  if (tid < 240) {
    int par = tid & 1;
    int h   = (tid >> 1) & 1;
    int tq  = tid >> 2;
    int ho  = h * FD;
#pragma unroll 1
    for (int half = 0; half < 2; ++half) {
      int r = half ? (T - 1 - tq) : tq;
      float q[FD];
#pragma unroll
      for (int f = 0; f < FD; ++f) q[f] = b2f(Os[r * STE + ho + f]);
      float m = -3e38f, l = 0.f;
      float acc[FD];
#pragma unroll
      for (int f = 0; f < FD; ++f) acc[f] = 0.f;
#pragma unroll 1
      for (int k = par; k <= r; k += 2) {
        const float4* kr = (const float4*)&Ks[k * STK + ho];
        float4 k0 = kr[0], k1 = kr[1], k2 = kr[2], k3 = kr[3];
        float s = q[0]*k0.x + q[1]*k0.y + q[2]*k0.z + q[3]*k0.w
                + q[4]*k1.x + q[5]*k1.y + q[6]*k1.z + q[7]*k1.w
                + q[8]*k2.x + q[9]*k2.y + q[10]*k2.z + q[11]*k2.w
                + q[12]*k3.x + q[13]*k3.y + q[14]*k3.z + q[15]*k3.w;
        s *= SCALE;
        float nm = fmaxf(m, s);
        float cf = __expf(m - nm);
        float p  = __expf(s - nm);
        l = l * cf + p;
        const float4* vr = (const float4*)&Vs[k * STK + ho];
        float4 v0 = vr[0], v1 = vr[1], v2 = vr[2], v3 = vr[3];
        acc[0]  = acc[0]*cf  + p*v0.x; acc[1]  = acc[1]*cf  + p*v0.y;
        acc[2]  = acc[2]*cf  + p*v0.z; acc[3]  = acc[3]*cf  + p*v0.w;
        acc[4]  = acc[4]*cf  + p*v1.x; acc[5]  = acc[5]*cf  + p*v1.y;
        acc[6]  = acc[6]*cf  + p*v1.z; acc[7]  = acc[7]*cf  + p*v1.w;
        acc[8]  = acc[8]*cf  + p*v2.x; acc[9]  = acc[9]*cf  + p*v2.y;
        acc[10] = acc[10]*cf + p*v2.z; acc[11] = acc[11]*cf + p*v2.w;
        acc[12] = acc[12]*cf + p*v3.x; acc[13] = acc[13]*cf + p*v3.y;
        acc[14] = acc[14]*cf + p*v3.z; acc[15] = acc[15]*cf + p*v3.w;
        m = nm;
      }
      // merge the two parity-partial states (lanes tid, tid^1)
      float m2 = __shfl_xor(m, 1, 64);
      float mm = fmaxf(m, m2);
      float cs = __expf(m - mm);
      float l2 = __shfl_xor(l, 1, 64);
      float c2 = __expf(m2 - mm);
      float rl = 1.f / (l * cs + l2 * c2);
#pragma unroll
      for (int f = 0; f < FD; ++f) {
        float a = acc[f] * cs;
        a += __shfl_xor(a, 1, 64);
        if ((f >> 3) == par)   // par0 writes f0..7, par1 writes f8..15
          Os[r * STE + ho + f] = __float2bfloat16(a * rl);
      }
    }
  }
  __syncthreads();

  // --- output projection + residual into Ks ---
  {
    const float* wog = tm_Wo + n * D * D;
    float wo[D];
#pragma unroll
    for (int d = 0; d < D; ++d) wo[d] = wog[d * D + e];
    float bov = tm_bo[n * D + e];
#pragma unroll
    for (int k = 0; k < T * D / 256; ++k) {
      int t = (tid + k * 256) >> 5;
      float a = bov;
#pragma unroll
      for (int d = 0; d < D; ++d) a += b2f(Os[t * STE + d]) * wo[d];
      Ks[t * STK + e] = a + b2f(Es[t * STE + e]);
    }
  }
  __syncthreads();

  // --- LayerNorm, one thread per row ---
  if (tid < T) {
    int t = tid;
    float mu = 0.f;
#pragma unroll
    for (int d = 0; d < D; ++d) mu += Ks[t * STK + d];
    mu *= (1.f / D);
    float var = 0.f;
#pragma unroll
    for (int d = 0; d < D; ++d) { float c = Ks[t * STK + d] - mu; var += c * c; }
    var *= (1.f / D);
    float r = rsqrtf(var + 1e-5f);
#pragma unroll
    for (int d = 0; d < D; ++d)
      Tn[((size_t)(b * T + t) * N + n) * D + d] =
          __float2bfloat16((Ks[t * STK + d] - mu) * r * ln_g[d] + ln_b[d]);
  }
}

// ---------------------------------------------------------------------------
// Spatial attention, fused per (b, t).  N=24 rows, 12.7 KB LDS.
// ---------------------------------------------------------------------------
__global__ __launch_bounds__(64) void spatial_kernel(
    const bf16* __restrict__ E, const float* __restrict__ WsC,
    const float* __restrict__ bsC, const float* __restrict__ sm_Wo,
    const float* __restrict__ sm_bo, const float* __restrict__ ln_g,
    const float* __restrict__ ln_b, bf16* __restrict__ Sn) {
  int b = blockIdx.x / T;
  int t = blockIdx.x % T;
  __shared__ float Es[N * ST], Ks[N * ST], Vs[N * ST], Os[N * ST];
  int tid = threadIdx.x;
  int e = tid & 31;

  for (int i = tid; i < N * D; i += 64) {
    int nn = i >> 5, d = i & 31;
    Es[nn * ST + d] = b2f(E[((size_t)(b * T + t) * N + nn) * D + d]);
  }
  __syncthreads();

  {
    const float* wqg = WsC + (0 * T + t) * D * D;
    const float* wkg = WsC + (1 * T + t) * D * D;
    float wq[D], wk[D];
#pragma unroll
    for (int d = 0; d < D; ++d) { wq[d] = wqg[d * D + e]; wk[d] = wkg[d * D + e]; }
    float bqv = bsC[(0 * T + t) * D + e];
    float bkv = bsC[(1 * T + t) * D + e];
#pragma unroll
    for (int k = 0; k < N * D / 64; ++k) {
      int nn = (tid + k * 64) >> 5;
      float aq = bqv, ak = bkv;
#pragma unroll
      for (int d = 0; d < D; ++d) {
        float x = Es[nn * ST + d];
        aq += x * wq[d];
        ak += x * wk[d];
      }
      Os[nn * ST + e] = aq;
      Ks[nn * ST + e] = ak;
    }
  }
  {
    const float* wvg = WsC + (2 * T + t) * D * D;
    float wv[D];
#pragma unroll
    for (int d = 0; d < D; ++d) wv[d] = wvg[d * D + e];
    float bvv = bsC[(2 * T + t) * D + e];
#pragma unroll
    for (int k = 0; k < N * D / 64; ++k) {
      int nn = (tid + k * 64) >> 5;
      float av = bvv;
#pragma unroll
      for (int d = 0; d < D; ++d) av += Es[nn * ST + d] * wv[d];
      Vs[nn * ST + e] = av;
    }
  }
  __syncthreads();

  if (tid < N * NH) {
    int nn = tid >> 1, h = tid & 1;
    int ho = h * FD;
    float q[FD];
#pragma unroll
    for (int f = 0; f < FD; ++f) q[f] = Os[nn * ST + ho + f];
    float sc[N];
    float m = -1e30f;
#pragma unroll
    for (int k = 0; k < N; ++k) {
      float s = 0.f;
#pragma unroll
      for (int f = 0; f < FD; ++f) s += q[f] * Ks[k * ST + ho + f];
      s *= SCALE;
      sc[k] = s;
      m = fmaxf(m, s);
    }
    float l = 0.f;
#pragma unroll
    for (int k = 0; k < N; ++k) { sc[k] = __expf(sc[k] - m); l += sc[k]; }
    float rl = 1.f / l;
#pragma unroll
    for (int f = 0; f < FD; ++f) {
      float a = 0.f;
#pragma unroll
      for (int k = 0; k < N; ++k) a += sc[k] * Vs[k * ST + ho + f];
      Os[nn * ST + ho + f] = a * rl;
    }
  }
  __syncthreads();

  {
    const float* wog = sm_Wo + t * D * D;
    float wo[D];
#pragma unroll
    for (int d = 0; d < D; ++d) wo[d] = wog[d * D + e];
    float bov = sm_bo[t * D + e];
#pragma unroll
    for (int k = 0; k < N * D / 64; ++k) {
      int nn = (tid + k * 64) >> 5;
      float a = bov;
#pragma unroll
      for (int d = 0; d < D; ++d) a += Os[nn * ST + d] * wo[d];
      Ks[nn * ST + e] = a + Es[nn * ST + e];
    }
  }
  __syncthreads();

  if (tid < N) {
    int nn = tid;
    float mu = 0.f;
#pragma unroll
    for (int d = 0; d < D; ++d) mu += Ks[nn * ST + d];
    mu *= (1.f / D);
    float var = 0.f;
#pragma unroll
    for (int d = 0; d < D; ++d) { float c = Ks[nn * ST + d] - mu; var += c * c; }
    var *= (1.f / D);
    float r = rsqrtf(var + 1e-5f);
#pragma unroll
    for (int d = 0; d < D; ++d)
      Sn[((size_t)(b * T + t) * N + nn) * D + d] =
          __float2bfloat16((Ks[nn * ST + d] - mu) * r * ln_g[d] + ln_b[d]);
  }
}

// ---------------------------------------------------------------------------
// ts = Tn + Sn; ff = relu(ts@W1+b1)@W2+b2; E = LN(ff + ts).  Row per thread.
// ---------------------------------------------------------------------------
__global__ __launch_bounds__(256) void ff_kernel(
    const bf16* __restrict__ Tn, const bf16* __restrict__ Sn,
    const float* __restrict__ W1, const float* __restrict__ b1,
    const float* __restrict__ W2, const float* __restrict__ b2,
    const float* __restrict__ ln_g, const float* __restrict__ ln_b,
    bf16* __restrict__ E) {
  __shared__ float w1[D * FF], w2[FF * D], bb1[FF], bb2[D], g[D], bbn[D];
  int tid = threadIdx.x;
  for (int i = tid; i < D * FF; i += 256) {
    w1[i] = W1[i];
    w2[i] = W2[i];
  }
  if (tid < FF) bb1[tid] = b1[tid];
  if (tid < D) {
    bb2[tid] = b2[tid];
    g[tid]   = ln_g[tid];
    bbn[tid] = ln_b[tid];
  }
  __syncthreads();
  int row = blockIdx.x * 256 + tid;
  if (row >= B * T * N) return;
  float ts[D];
#pragma unroll
  for (int d = 0; d < D; ++d)
    ts[d] = b2f(Tn[(size_t)row * D + d]) + b2f(Sn[(size_t)row * D + d]);
  float h[FF];
#pragma unroll
  for (int j = 0; j < FF; ++j) {
    float a = bb1[j];
#pragma unroll
    for (int d = 0; d < D; ++d) a += ts[d] * w1[d * FF + j];
    h[j] = fmaxf(a, 0.f);
  }
  float x[D];
  float mu = 0.f;
#pragma unroll
  for (int e = 0; e < D; ++e) {
    float a = bb2[e];
#pragma unroll
    for (int j = 0; j < FF; ++j) a += h[j] * w2[j * D + e];
    a += ts[e];
    x[e] = a;
    mu += a;
  }
  mu *= (1.f / D);
  float var = 0.f;
#pragma unroll
  for (int e = 0; e < D; ++e) { float c = x[e] - mu; var += c * c; }
  var *= (1.f / D);
  float r = rsqrtf(var + 1e-5f);
#pragma unroll
  for (int e = 0; e < D; ++e)
    E[(size_t)row * D + e] = __float2bfloat16((x[e] - mu) * r * g[e] + bbn[e]);
}

// ---------------------------------------------------------------------------
// out[b,t,n,m] = E[b,t,n,:]@op_W[n,:,m] + op_b[n,m] + X[b,t,n*M+m]  (f32 out)
// ---------------------------------------------------------------------------
__global__ __launch_bounds__(256) void out_kernel(
    const bf16* __restrict__ E, const float* __restrict__ op_W,
    const float* __restrict__ op_b, const float* __restrict__ X,
    float* __restrict__ out) {
  int idx = blockIdx.x * 256 + threadIdx.x;
  if (idx >= B * T * N * M) return;
  int m  = idx % M;
  int n  = (idx / M) % N;
  int bt = idx / (M * N);
  float acc = op_b[n * M + m];
  const bf16* e = E + ((size_t)bt * N + n) * D;
#pragma unroll
  for (int d = 0; d < D; ++d) acc += b2f(e[d]) * op_W[(n * D + d) * M + m];
  acc += X[idx];
  out[idx] = acc;
}

// ---------------------------------------------------------------------------
extern "C" void kernel_launch(void* const* d_in, const int* in_sizes, int n_in,
                              void* d_out, int out_size, void* d_ws, size_t ws_size,
                              hipStream_t stream) {
  const float* X     = (const float*)d_in[0];
  const float* pe    = (const float*)d_in[1];
  const float* E_W   = (const float*)d_in[2];
  const float* E_b   = (const float*)d_in[3];
  const float* tq_W  = (const float*)d_in[4];
  const float* tq_b  = (const float*)d_in[5];
  const float* tk_W  = (const float*)d_in[6];
  const float* tk_b  = (const float*)d_in[7];
  const float* tv_W  = (const float*)d_in[8];
  const float* tv_b  = (const float*)d_in[9];
  const float* tm_Wq = (const float*)d_in[10];
  const float* tm_bq = (const float*)d_in[11];
  const float* tm_Wk = (const float*)d_in[12];
  const float* tm_bk = (const float*)d_in[13];
  const float* tm_Wv = (const float*)d_in[14];
  const float* tm_bv = (const float*)d_in[15];
  const float* tm_Wo = (const float*)d_in[16];
  const float* tm_bo = (const float*)d_in[17];
  const float* sq_W  = (const float*)d_in[18];
  const float* sq_b  = (const float*)d_in[19];
  const float* sk_W  = (const float*)d_in[20];
  const float* sk_b  = (const float*)d_in[21];
  const float* sv_W  = (const float*)d_in[22];
  const float* sv_b  = (const float*)d_in[23];
  const float* sm_Wq = (const float*)d_in[24];
  const float* sm_bq = (const float*)d_in[25];
  const float* sm_Wk = (const float*)d_in[26];
  const float* sm_bk = (const float*)d_in[27];
  const float* sm_Wv = (const float*)d_in[28];
  const float* sm_bv = (const float*)d_in[29];
  const float* sm_Wo = (const float*)d_in[30];
  const float* sm_bo = (const float*)d_in[31];
  const float* ff1_W = (const float*)d_in[32];
  const float* ff1_b = (const float*)d_in[33];
  const float* ff2_W = (const float*)d_in[34];
  const float* ff2_b = (const float*)d_in[35];
  const float* ln_g  = (const float*)d_in[36];
  const float* ln_b  = (const float*)d_in[37];
  const float* op_W  = (const float*)d_in[38];
  const float* op_b  = (const float*)d_in[39];
  float* out = (float*)d_out;

  // workspace: f32 composed weights first, then bf16 activations (~37.2 MB)
  float* WtC = (float*)d_ws;                         // 3*N*D*D
  float* btC = WtC + 3 * N * D * D;                  // 3*N*D
  float* WsC = btC + 3 * N * D;                      // 3*T*D*D
  float* bsC = WsC + 3 * T * D * D;                  // 3*T*D
  size_t act = (size_t)B * T * N * D;
  bf16* Ebuf = (bf16*)(bsC + 3 * T * D);
  bf16* Tn   = Ebuf + act;
  bf16* Sn   = Tn + act;

  compose3_kernel<<<3 * N, 256, 0, stream>>>(
      tq_W, tq_b, tm_Wq, tm_bq, tk_W, tk_b, tm_Wk, tm_bk,
      tv_W, tv_b, tm_Wv, tm_bv, WtC, btC, N);
  compose3_kernel<<<3 * T, 256, 0, stream>>>(
      sq_W, sq_b, sm_Wq, sm_bq, sk_W, sk_b, sm_Wk, sm_bk,
      sv_W, sv_b, sm_Wv, sm_bv, WsC, bsC, T);

  embed_kernel<<<(B * T * N * D) / 256, 256, 0, stream>>>(X, pe, E_W, E_b, Ebuf);

  for (int l = 0; l < L; ++l) {
    temporal_kernel<<<B * N, 256, 0, stream>>>(Ebuf, WtC, btC, tm_Wo, tm_bo, ln_g, ln_b, Tn);
    spatial_kernel<<<B * T, 64, 0, stream>>>(Ebuf, WsC, bsC, sm_Wo, sm_bo, ln_g, ln_b, Sn);
    ff_kernel<<<(B * T * N) / 256, 256, 0, stream>>>(Tn, Sn, ff1_W, ff1_b, ff2_W, ff2_b, ln_g, ln_b, Ebuf);
  }

  out_kernel<<<(B * T * N * M) / 256, 256, 0, stream>>>(Ebuf, op_W, op_b, X, out);
}